// Round 1
// baseline (124.878 us; speedup 1.0000x reference)
//
#include <hip/hip_runtime.h>
#include <hip/hip_bf16.h>

// Problem constants
#define BB 16
#define SS 1024
#define DD 384
#define HH 6
#define KK 9
#define KH 54      // K*H
#define OUTD 384
#define NKT 12     // K-steps: 384/32
#define VLD 392    // LDS leading dim (bf16): 784 B/row -> 4-bank shift/row, <=2-way (free)
#define RPB 32     // rows (seq positions) per block
#define NTH 512    // threads per block (8 waves)

typedef __attribute__((ext_vector_type(4))) float floatx4;
typedef __attribute__((ext_vector_type(8))) __bf16 bf16x8;
typedef __attribute__((ext_vector_type(4))) __bf16 bf16x4;

// ---------------------------------------------------------------------------
// Kernel 0: cast + swizzle weights into MFMA B-fragment order (unchanged).
// WkT: 4 ntiles (54 rows zero-padded to 64) x 12 ksteps x 64 lanes x 8 bf16.
// WpT: 24 ntiles x 12 ksteps x 64 lanes x 8 bf16.
// Fragment: lane = n_in_tile(0..15) + 16*k_quad; elems = 8 consecutive k.
// ---------------------------------------------------------------------------
__global__ __launch_bounds__(256) void cast_kernel(const float* __restrict__ Wk,
                                                   const float* __restrict__ Wp,
                                                   __bf16* __restrict__ WkT,
                                                   __bf16* __restrict__ WpT) {
    int i = blockIdx.x * 256 + threadIdx.x;
    if (i < 4 * NKT * 64 * 8) {                    // 24576 elems of WkT
        int e = i & 7, lane = (i >> 3) & 63, t = i >> 9;
        int kstep = t % NKT, ntile = t / NKT;
        int row = ntile * 16 + (lane & 15);
        int col = kstep * 32 + ((lane >> 4) << 3) + e;
        WkT[i] = (row < KH) ? (__bf16)Wk[row * DD + col] : (__bf16)0.0f;
    } else if (i < 24576 + 24 * NKT * 64 * 8) {    // 147456 elems of WpT
        int j = i - 24576;
        int e = j & 7, lane = (j >> 3) & 63, t = j >> 9;
        int kstep = t % NKT, ntile = t / NKT;
        int row = ntile * 16 + (lane & 15);
        int col = kstep * 32 + ((lane >> 4) << 3) + e;
        WpT[j] = (__bf16)Wp[row * DD + col];
    }
}

// ---------------------------------------------------------------------------
// Kernel 1: fused, 32 seq rows / block, 512 threads (8 waves), grid 512.
// LDS: vqS 40*VLD*2 = 31360 | dkS 32*56*4 = 7168 | union(lgS 8448 / aS 25088)
//   total 63616 B -> 2 blocks/CU, 16 waves/CU (same occupancy as before).
// Changes vs prior version:
//  * v window prefetched into 8x float4 REGISTERS at kernel start (issued
//    right after the q/ks loads) -> the second HBM round-trip no longer
//    serializes behind phases 1-3a; one exposed HBM latency instead of two.
//  * 32-row blocks: phase-5 keeps acc[2][3] and reuses each WpT B-fragment
//    for TWO row-tiles -> WpT L2 traffic halved (302 MB -> 151 MB).
//  * v halo 40 rows / 32 outputs (1.25x) vs 24/16 (1.5x) -> -6 MB HBM fetch.
// ---------------------------------------------------------------------------
__global__ __launch_bounds__(NTH, 4) void fused_kernel(const float* __restrict__ q,
                                                       const float* __restrict__ ks,
                                                       const float* __restrict__ v,
                                                       const __bf16* __restrict__ WkT,
                                                       const float* __restrict__ bk,
                                                       const __bf16* __restrict__ WpT,
                                                       const float* __restrict__ bp,
                                                       float* __restrict__ out) {
    __shared__ __bf16 vqS[40 * VLD];                   // 31360 B (qk rows 0..31, then v rows 0..39)
    __shared__ float  dkS[RPB * 56];                   //  7168 B
    __shared__ __align__(16) char uS[RPB * VLD * 2];   // 25088 B: lgS, later aS
    float*  lgS = (float*)uS;                          // [32][66] logits
    __bf16* aS  = (__bf16*)uS;                         // [32][VLD] conv output

    const int tid  = threadIdx.x;
    const int wave = tid >> 6;
    const int lane = tid & 63;
    const int m0   = blockIdx.x * RPB;
    const int b    = blockIdx.x >> 5;                  // 32 blocks per batch
    const int s0   = (blockIdx.x & 31) * RPB;
    const int fr   = lane & 15;
    const int fk   = (lane >> 4) * 8;
    const int col_in = lane & 15;
    const int rgrp   = (lane >> 4) * 4;

    // ---- phase 1: stage qk = q*ks as bf16, 32x384, coalesced ----
    {
        const float* qb = q  + (size_t)m0 * DD;
        const float* kb = ks + (size_t)m0 * DD;
#pragma unroll
        for (int it = 0; it < 6; ++it) {
            int c = tid + it * NTH;                    // 0..3071 float4-chunks
            int row = c / 96, col = (c % 96) * 4;
            floatx4 qv = *reinterpret_cast<const floatx4*>(qb + (size_t)row * DD + col);
            floatx4 kv = *reinterpret_cast<const floatx4*>(kb + (size_t)row * DD + col);
            floatx4 pr = qv * kv;
            bf16x4 pk = { (__bf16)pr.x, (__bf16)pr.y, (__bf16)pr.z, (__bf16)pr.w };
            *reinterpret_cast<bf16x4*>(&vqS[row * VLD + col]) = pk;
        }
    }

    // ---- v PREFETCH into registers (issued pre-barrier, after q/ks loads;
    //      consumed in phase 3b). Branchless clamp+select handles seq edges. ----
    floatx4 vpre[8];
    {
        const float* vb = v + (size_t)b * SS * DD;
#pragma unroll
        for (int it = 0; it < 8; ++it) {
            int c = tid + it * NTH;                    // 0..4095 (3840 live)
            int row = c / 96, col = (c % 96) * 4;
            int r = s0 + row - 4;
            int rc = r < 0 ? 0 : (r > SS - 1 ? SS - 1 : r);
            floatx4 val = *reinterpret_cast<const floatx4*>(vb + (size_t)rc * DD + col);
            if (r < 0 || r >= SS) val = floatx4{0.0f, 0.0f, 0.0f, 0.0f};
            vpre[it] = val;
        }
    }
    __syncthreads();

    // ---- phase 2: logits MFMA. wave = (rowtile, ntile): rt=w>>2, nt=w&3 ----
    {
        const int rt = wave >> 2;
        const int nt = wave & 3;
        floatx4 acc = {};
#pragma unroll
        for (int s = 0; s < NKT; ++s) {
            bf16x8 af = *reinterpret_cast<const bf16x8*>(
                &vqS[(rt * 16 + fr) * VLD + s * 32 + fk]);
            bf16x8 bfrag = *reinterpret_cast<const bf16x8*>(
                WkT + (((nt * NKT + s) * 64 + lane) << 3));
            acc = __builtin_amdgcn_mfma_f32_16x16x32_bf16(af, bfrag, acc, 0, 0, 0);
        }
        // C/D layout: col = lane&15, row = (lane>>4)*4 + reg
#pragma unroll
        for (int r = 0; r < 4; ++r)
            lgS[(rt * 16 + rgrp + r) * 66 + nt * 16 + col_in] = acc[r];
    }
    __syncthreads();

    // ---- phase 3a: softmax over 9 taps (192 tasks) -> dkS ----
    if (tid < RPB * HH) {
        int row = tid / HH, h = tid % HH;
        float lg[KK];
        float mx = -1e30f;
#pragma unroll
        for (int k = 0; k < KK; ++k) {
            float s = lgS[row * 66 + h * KK + k] + bk[h * KK + k];
            lg[k] = s;
            mx = fmaxf(mx, s);
        }
        float sum = 0.0f;
#pragma unroll
        for (int k = 0; k < KK; ++k) { lg[k] = __expf(lg[k] - mx); sum += lg[k]; }
        float inv = 1.0f / sum;
#pragma unroll
        for (int k = 0; k < KK; ++k) dkS[row * 56 + h * KK + k] = lg[k] * inv;
    }

    // ---- phase 3b: spill prefetched v window (rows s0-4..s0+35) to LDS ----
    {
#pragma unroll
        for (int it = 0; it < 8; ++it) {
            int c = tid + it * NTH;
            if (c < 3840) {                            // 40 rows x 96 chunks
                int row = c / 96, col = (c % 96) * 4;
                floatx4 val = vpre[it];
                bf16x4 vk = { (__bf16)val.x, (__bf16)val.y, (__bf16)val.z, (__bf16)val.w };
                *reinterpret_cast<bf16x4*>(&vqS[row * VLD + col]) = vk;
            }
        }
    }
    __syncthreads();

    // ---- phase 4: 9-tap conv from LDS -> A-tile in LDS (overlays lgS) ----
#pragma unroll
    for (int it = 0; it < 6; ++it) {
        int p = tid + it * NTH;                        // 0..3071
        int row = p / 96, c4 = p % 96;
        int h = c4 >> 4;
        const float* dkr = &dkS[row * 56 + h * KK];
        floatx4 a = {};
#pragma unroll
        for (int k = 0; k < KK; ++k) {
            bf16x4 w = *reinterpret_cast<const bf16x4*>(&vqS[(row + k) * VLD + c4 * 4]);
            floatx4 wf = { (float)w[0], (float)w[1], (float)w[2], (float)w[3] };
            a += wf * dkr[k];
        }
        bf16x4 o = { (__bf16)a.x, (__bf16)a.y, (__bf16)a.z, (__bf16)a.w };
        *reinterpret_cast<bf16x4*>(&aS[row * VLD + c4 * 4]) = o;
    }
    __syncthreads();

    // ---- phase 5: C = A @ Wp^T + bp. wave = 3 ntiles; each B-fragment is
    //      loaded ONCE and used for BOTH 16-row tiles (acc[2][3]). ----
    {
        const int nt0 = wave * 3;
        floatx4 acc[2][3] = {};
#pragma unroll
        for (int s = 0; s < NKT; ++s) {
            bf16x8 a0 = *reinterpret_cast<const bf16x8*>(&aS[fr * VLD + s * 32 + fk]);
            bf16x8 a1 = *reinterpret_cast<const bf16x8*>(&aS[(16 + fr) * VLD + s * 32 + fk]);
#pragma unroll
            for (int j = 0; j < 3; ++j) {
                bf16x8 bfrag = *reinterpret_cast<const bf16x8*>(
                    WpT + ((((nt0 + j) * NKT + s) * 64 + lane) << 3));
                acc[0][j] = __builtin_amdgcn_mfma_f32_16x16x32_bf16(a0, bfrag, acc[0][j], 0, 0, 0);
                acc[1][j] = __builtin_amdgcn_mfma_f32_16x16x32_bf16(a1, bfrag, acc[1][j], 0, 0, 0);
            }
        }
        float* ob = out + (size_t)m0 * OUTD;
#pragma unroll
        for (int j = 0; j < 3; ++j) {
            int col = (nt0 + j) * 16 + col_in;
            float bv = bp[col];
#pragma unroll
            for (int rt = 0; rt < 2; ++rt)
#pragma unroll
                for (int r = 0; r < 4; ++r)
                    ob[(size_t)(rt * 16 + rgrp + r) * OUTD + col] = acc[rt][j][r] + bv;
        }
    }
}

// ---------------------------------------------------------------------------
extern "C" void kernel_launch(void* const* d_in, const int* in_sizes, int n_in,
                              void* d_out, int out_size, void* d_ws, size_t ws_size,
                              hipStream_t stream) {
    const float* q  = (const float*)d_in[0];
    const float* ks = (const float*)d_in[1];
    const float* v  = (const float*)d_in[2];
    const float* Wk = (const float*)d_in[3];
    const float* bk = (const float*)d_in[4];
    const float* Wp = (const float*)d_in[5];
    const float* bp = (const float*)d_in[6];
    float* out = (float*)d_out;

    // ws layout: WkT bf16 49152 B | WpT bf16 294912 B
    __bf16* WkT = (__bf16*)d_ws;
    __bf16* WpT = (__bf16*)((char*)d_ws + 49152);

    cast_kernel<<<(24576 + 147456 + 255) / 256, 256, 0, stream>>>(Wk, Wp, WkT, WpT);
    fused_kernel<<<(BB * SS) / RPB, NTH, 0, stream>>>(q, ks, v, WkT, bk, WpT, bp, out);
}

// Round 2
// 122.854 us; speedup vs baseline: 1.0165x; 1.0165x over previous
//
#include <hip/hip_runtime.h>
#include <hip/hip_bf16.h>

// Problem constants
#define BB 16
#define SS 1024
#define DD 384
#define HH 6
#define KK 9
#define KH 54      // K*H
#define OUTD 384
#define NKT 12     // K-steps: 384/32
#define VLD 392    // LDS leading dim (bf16): 784 B/row -> 4-bank shift/row, <=2-way (free)
#define RPB 32     // rows (seq positions) per block
#define NTH 512    // threads per block (8 waves)

typedef __attribute__((ext_vector_type(4))) float floatx4;
typedef __attribute__((ext_vector_type(8))) __bf16 bf16x8;
typedef __attribute__((ext_vector_type(4))) __bf16 bf16x4;

// ---------------------------------------------------------------------------
// Kernel 0: cast + swizzle weights into MFMA B-fragment order (unchanged).
// WkT: 4 ntiles (54 rows zero-padded to 64) x 12 ksteps x 64 lanes x 8 bf16.
// WpT: 24 ntiles x 12 ksteps x 64 lanes x 8 bf16.
// ---------------------------------------------------------------------------
__global__ __launch_bounds__(256) void cast_kernel(const float* __restrict__ Wk,
                                                   const float* __restrict__ Wp,
                                                   __bf16* __restrict__ WkT,
                                                   __bf16* __restrict__ WpT) {
    int i = blockIdx.x * 256 + threadIdx.x;
    if (i < 4 * NKT * 64 * 8) {                    // 24576 elems of WkT
        int e = i & 7, lane = (i >> 3) & 63, t = i >> 9;
        int kstep = t % NKT, ntile = t / NKT;
        int row = ntile * 16 + (lane & 15);
        int col = kstep * 32 + ((lane >> 4) << 3) + e;
        WkT[i] = (row < KH) ? (__bf16)Wk[row * DD + col] : (__bf16)0.0f;
    } else if (i < 24576 + 24 * NKT * 64 * 8) {    // 147456 elems of WpT
        int j = i - 24576;
        int e = j & 7, lane = (j >> 3) & 63, t = j >> 9;
        int kstep = t % NKT, ntile = t / NKT;
        int row = ntile * 16 + (lane & 15);
        int col = kstep * 32 + ((lane >> 4) << 3) + e;
        WpT[j] = (__bf16)Wp[row * DD + col];
    }
}

// ---------------------------------------------------------------------------
// Kernel 1: fused, 32 rows/block, 512 threads (8 waves), grid 512, 2 blk/CU.
// This revision targets MEMORY-LEVEL PARALLELISM (round-1 VGPR=52 showed the
// compiler was serializing load->cvt->ds_write, throttling the HBM burst):
//  * phase 1 issues ALL 12 q/ks loads + ALL 8 v loads into registers before
//    the first conversion: 20 outstanding 16B loads/thread; first use waits
//    vmcnt(18) so q/ks convert while v is still in flight.
//  * phase 2: 2-deep rolling register prefetch of WkT B-fragments.
//  * phase 5: 2-deep rolling prefetch of WpT B-fragments; kstep-0 fragments
//    are issued BEFORE the conv barrier (read-only, no in-block dependency)
//    so their L2 latency hides under the barrier + conv tail.
// ---------------------------------------------------------------------------
__global__ __launch_bounds__(NTH, 4) void fused_kernel(const float* __restrict__ q,
                                                       const float* __restrict__ ks,
                                                       const float* __restrict__ v,
                                                       const __bf16* __restrict__ WkT,
                                                       const float* __restrict__ bk,
                                                       const __bf16* __restrict__ WpT,
                                                       const float* __restrict__ bp,
                                                       float* __restrict__ out) {
    __shared__ __bf16 vqS[40 * VLD];                   // 31360 B (qk rows 0..31, then v rows 0..39)
    __shared__ float  dkS[RPB * 56];                   //  7168 B
    __shared__ __align__(16) char uS[RPB * VLD * 2];   // 25088 B: lgS, later aS
    float*  lgS = (float*)uS;                          // [32][66] logits
    __bf16* aS  = (__bf16*)uS;                         // [32][VLD] conv output

    const int tid  = threadIdx.x;
    const int wave = tid >> 6;
    const int lane = tid & 63;
    const int m0   = blockIdx.x * RPB;
    const int b    = blockIdx.x >> 5;                  // 32 blocks per batch
    const int s0   = (blockIdx.x & 31) * RPB;
    const int fr   = lane & 15;
    const int fk   = (lane >> 4) * 8;
    const int col_in = lane & 15;
    const int rgrp   = (lane >> 4) * 4;

    // ---- phase 1: BURST-issue q/ks (12 loads) + v window (8 loads) ----
    floatx4 qv[6], kv[6], vpre[8];
    {
        const float* qb = q  + (size_t)m0 * DD;
        const float* kb = ks + (size_t)m0 * DD;
#pragma unroll
        for (int it = 0; it < 6; ++it) {
            int c = tid + it * NTH;                    // 0..3071 float4-chunks
            int row = c / 96, col = (c % 96) * 4;
            qv[it] = *reinterpret_cast<const floatx4*>(qb + (size_t)row * DD + col);
            kv[it] = *reinterpret_cast<const floatx4*>(kb + (size_t)row * DD + col);
        }
        const float* vb = v + (size_t)b * SS * DD;
#pragma unroll
        for (int it = 0; it < 8; ++it) {
            int c = tid + it * NTH;                    // 0..4095 (3840 live)
            int row = c / 96, col = (c % 96) * 4;
            int r = s0 + row - 4;
            int rc = r < 0 ? 0 : (r > SS - 1 ? SS - 1 : r);
            vpre[it] = *reinterpret_cast<const floatx4*>(vb + (size_t)rc * DD + col);
        }
        // convert + stage qk while v loads are still in flight
#pragma unroll
        for (int it = 0; it < 6; ++it) {
            int c = tid + it * NTH;
            int row = c / 96, col = (c % 96) * 4;
            floatx4 pr = qv[it] * kv[it];
            bf16x4 pk = { (__bf16)pr.x, (__bf16)pr.y, (__bf16)pr.z, (__bf16)pr.w };
            *reinterpret_cast<bf16x4*>(&vqS[row * VLD + col]) = pk;
        }
    }
    __syncthreads();

    // ---- phase 2: logits MFMA, wave=(rowtile rt, ntile nt), 2-deep WkT pf ----
    {
        const int rt = wave >> 2;
        const int nt = wave & 3;
        const __bf16* wkb = WkT + (((nt * NKT) * 64 + lane) << 3);
        bf16x8 wf0 = *reinterpret_cast<const bf16x8*>(wkb);
        bf16x8 wf1;
        floatx4 acc = {};
#pragma unroll
        for (int s = 0; s < NKT; ++s) {
            if (s + 1 < NKT) {
                const __bf16* nb = wkb + ((size_t)(s + 1) << 9);
                if ((s & 1) == 0) wf1 = *reinterpret_cast<const bf16x8*>(nb);
                else              wf0 = *reinterpret_cast<const bf16x8*>(nb);
            }
            bf16x8 af = *reinterpret_cast<const bf16x8*>(
                &vqS[(rt * 16 + fr) * VLD + s * 32 + fk]);
            acc = __builtin_amdgcn_mfma_f32_16x16x32_bf16(
                af, (s & 1) == 0 ? wf0 : wf1, acc, 0, 0, 0);
        }
        // C/D layout: col = lane&15, row = (lane>>4)*4 + reg
#pragma unroll
        for (int r = 0; r < 4; ++r)
            lgS[(rt * 16 + rgrp + r) * 66 + nt * 16 + col_in] = acc[r];
    }
    __syncthreads();

    // ---- phase 3a: softmax over 9 taps (192 tasks) -> dkS ----
    if (tid < RPB * HH) {
        int row = tid / HH, h = tid % HH;
        float lg[KK];
        float mx = -1e30f;
#pragma unroll
        for (int k = 0; k < KK; ++k) {
            float s = lgS[row * 66 + h * KK + k] + bk[h * KK + k];
            lg[k] = s;
            mx = fmaxf(mx, s);
        }
        float sum = 0.0f;
#pragma unroll
        for (int k = 0; k < KK; ++k) { lg[k] = __expf(lg[k] - mx); sum += lg[k]; }
        float inv = 1.0f / sum;
#pragma unroll
        for (int k = 0; k < KK; ++k) dkS[row * 56 + h * KK + k] = lg[k] * inv;
    }

    // ---- phase 3b: spill prefetched v window (rows s0-4..s0+35) to LDS ----
    {
#pragma unroll
        for (int it = 0; it < 8; ++it) {
            int c = tid + it * NTH;
            if (c < 3840) {                            // 40 rows x 96 chunks
                int row = c / 96, col = (c % 96) * 4;
                int r = s0 + row - 4;
                floatx4 val = vpre[it];
                if (r < 0 || r >= SS) val = floatx4{0.0f, 0.0f, 0.0f, 0.0f};
                bf16x4 vk = { (__bf16)val.x, (__bf16)val.y, (__bf16)val.z, (__bf16)val.w };
                *reinterpret_cast<bf16x4*>(&vqS[row * VLD + col]) = vk;
            }
        }
    }
    __syncthreads();

    // ---- phase 4: 9-tap conv from LDS -> A-tile in LDS (overlays lgS) ----
#pragma unroll
    for (int it = 0; it < 6; ++it) {
        int p = tid + it * NTH;                        // 0..3071
        int row = p / 96, c4 = p % 96;
        int h = c4 >> 4;
        const float* dkr = &dkS[row * 56 + h * KK];
        floatx4 a = {};
#pragma unroll
        for (int k = 0; k < KK; ++k) {
            bf16x4 w = *reinterpret_cast<const bf16x4*>(&vqS[(row + k) * VLD + c4 * 4]);
            floatx4 wf = { (float)w[0], (float)w[1], (float)w[2], (float)w[3] };
            a += wf * dkr[k];
        }
        bf16x4 o = { (__bf16)a.x, (__bf16)a.y, (__bf16)a.z, (__bf16)a.w };
        *reinterpret_cast<bf16x4*>(&aS[row * VLD + c4 * 4]) = o;
    }

    // ---- phase 5 prologue: issue kstep-0 WpT fragments BEFORE the barrier
    //      (read-only global; latency hides under barrier + conv tail) ----
    const int nt0 = wave * 3;
    const __bf16* wpb = WpT + (((nt0 * NKT) * 64 + lane) << 3);
    bf16x8 bfr[2][3];
#pragma unroll
    for (int j = 0; j < 3; ++j)
        bfr[0][j] = *reinterpret_cast<const bf16x8*>(wpb + ((size_t)(j * NKT) << 9));
    __syncthreads();

    // ---- phase 5: C = A @ Wp^T + bp, 2-deep rolling B prefetch ----
    {
        floatx4 acc[2][3] = {};
#pragma unroll
        for (int s = 0; s < NKT; ++s) {
            const int cur = s & 1, nxt = cur ^ 1;
            if (s + 1 < NKT) {
#pragma unroll
                for (int j = 0; j < 3; ++j)
                    bfr[nxt][j] = *reinterpret_cast<const bf16x8*>(
                        wpb + ((size_t)(j * NKT + s + 1) << 9));
            }
            bf16x8 a0 = *reinterpret_cast<const bf16x8*>(&aS[fr * VLD + s * 32 + fk]);
            bf16x8 a1 = *reinterpret_cast<const bf16x8*>(&aS[(16 + fr) * VLD + s * 32 + fk]);
#pragma unroll
            for (int j = 0; j < 3; ++j) {
                acc[0][j] = __builtin_amdgcn_mfma_f32_16x16x32_bf16(a0, bfr[cur][j], acc[0][j], 0, 0, 0);
                acc[1][j] = __builtin_amdgcn_mfma_f32_16x16x32_bf16(a1, bfr[cur][j], acc[1][j], 0, 0, 0);
            }
        }
        float* ob = out + (size_t)m0 * OUTD;
#pragma unroll
        for (int j = 0; j < 3; ++j) {
            int col = (nt0 + j) * 16 + col_in;
            float bv = bp[col];
#pragma unroll
            for (int rt = 0; rt < 2; ++rt)
#pragma unroll
                for (int r = 0; r < 4; ++r)
                    ob[(size_t)(rt * 16 + rgrp + r) * OUTD + col] = acc[rt][j][r] + bv;
        }
    }
}

// ---------------------------------------------------------------------------
extern "C" void kernel_launch(void* const* d_in, const int* in_sizes, int n_in,
                              void* d_out, int out_size, void* d_ws, size_t ws_size,
                              hipStream_t stream) {
    const float* q  = (const float*)d_in[0];
    const float* ks = (const float*)d_in[1];
    const float* v  = (const float*)d_in[2];
    const float* Wk = (const float*)d_in[3];
    const float* bk = (const float*)d_in[4];
    const float* Wp = (const float*)d_in[5];
    const float* bp = (const float*)d_in[6];
    float* out = (float*)d_out;

    // ws layout: WkT bf16 49152 B | WpT bf16 294912 B
    __bf16* WkT = (__bf16*)d_ws;
    __bf16* WpT = (__bf16*)((char*)d_ws + 49152);

    cast_kernel<<<(24576 + 147456 + 255) / 256, 256, 0, stream>>>(Wk, Wp, WkT, WpT);
    fused_kernel<<<(BB * SS) / RPB, NTH, 0, stream>>>(q, ks, v, WkT, bk, WpT, bp, out);
}